// Round 1
// baseline (916.591 us; speedup 1.0000x reference)
//
#include <hip/hip_runtime.h>
#include <stdint.h>

#define QMAX_F 127.0f

typedef int    i32x4  __attribute__((ext_vector_type(4)));
typedef float  f32x4  __attribute__((ext_vector_type(4)));
typedef int8_t i8x16  __attribute__((ext_vector_type(16)));

#define GLOBAL_AS(p) ((const __attribute__((address_space(1))) void*)(p))
#define LDS_AS(p)    ((__attribute__((address_space(3))) void*)(p))

// ---------------------------------------------------------------- init
__global__ void init_ws_kernel(unsigned* absmax_bits) {
    if (threadIdx.x == 0) absmax_bits[0] = 0u;
}

// ------------------------------------------------------ global absmax(x)
__global__ void absmax_x_kernel(const float* __restrict__ x, size_t n4,
                                unsigned* __restrict__ out_bits) {
    size_t stride = (size_t)gridDim.x * blockDim.x;
    float m = 0.f;
    for (size_t i = (size_t)blockIdx.x * blockDim.x + threadIdx.x; i < n4; i += stride) {
        f32x4 v = reinterpret_cast<const f32x4*>(x)[i];
        m = fmaxf(m, fmaxf(fmaxf(fabsf(v[0]), fabsf(v[1])),
                           fmaxf(fabsf(v[2]), fabsf(v[3]))));
    }
    #pragma unroll
    for (int off = 32; off > 0; off >>= 1) m = fmaxf(m, __shfl_down(m, off));
    __shared__ float red[4];
    int lane = threadIdx.x & 63, wid = threadIdx.x >> 6;
    if (lane == 0) red[wid] = m;
    __syncthreads();
    if (threadIdx.x == 0) {
        m = fmaxf(fmaxf(red[0], red[1]), fmaxf(red[2], red[3]));
        atomicMax(out_bits, __float_as_uint(m));
    }
}

// ------------------------------------------------- per-row absmax(weight)
__global__ void rowmax_w_kernel(const float* __restrict__ w,
                                float* __restrict__ rowmax, int K) {
    int row = blockIdx.x;
    const f32x4* wr4 = reinterpret_cast<const f32x4*>(w + (size_t)row * K);
    float m = 0.f;
    for (int j = threadIdx.x; j < (K >> 2); j += blockDim.x) {
        f32x4 v = wr4[j];
        m = fmaxf(m, fmaxf(fmaxf(fabsf(v[0]), fabsf(v[1])),
                           fmaxf(fabsf(v[2]), fabsf(v[3]))));
    }
    #pragma unroll
    for (int off = 32; off > 0; off >>= 1) m = fmaxf(m, __shfl_down(m, off));
    __shared__ float red[4];
    int lane = threadIdx.x & 63, wid = threadIdx.x >> 6;
    if (lane == 0) red[wid] = m;
    __syncthreads();
    if (threadIdx.x == 0)
        rowmax[row] = fmaxf(fmaxf(red[0], red[1]), fmaxf(red[2], red[3]));
}

// ------------------------------------------------------------ quantize x
__global__ void quant_x_kernel(const float* __restrict__ x, int8_t* __restrict__ xq,
                               const unsigned* __restrict__ mx_bits, size_t n16) {
    float sx = fmaxf(__uint_as_float(*mx_bits), 1e-8f) / QMAX_F;
    size_t stride = (size_t)gridDim.x * blockDim.x;
    for (size_t i = (size_t)blockIdx.x * blockDim.x + threadIdx.x; i < n16; i += stride) {
        i8x16 q;
        #pragma unroll
        for (int j = 0; j < 4; ++j) {
            f32x4 v = reinterpret_cast<const f32x4*>(x)[i * 4 + j];
            #pragma unroll
            for (int k = 0; k < 4; ++k) {
                float t = fminf(fmaxf(v[k] / sx, -QMAX_F), QMAX_F);
                q[j * 4 + k] = (int8_t)__float2int_rn(t);
            }
        }
        reinterpret_cast<i8x16*>(xq)[i] = q;
    }
}

// ------------------------------------------------------------ quantize w
__global__ void quant_w_kernel(const float* __restrict__ w, int8_t* __restrict__ wq,
                               const float* __restrict__ rowmax,
                               float* __restrict__ scale_w, int K) {
    int row = blockIdx.x;
    float sw = fmaxf(rowmax[row], 1e-8f) / QMAX_F;
    if (threadIdx.x == 0) scale_w[row] = sw;
    const f32x4* src = reinterpret_cast<const f32x4*>(w + (size_t)row * K);
    int8_t* dst = wq + (size_t)row * K;
    for (int base = threadIdx.x * 16; base < K; base += blockDim.x * 16) {
        i8x16 q;
        #pragma unroll
        for (int j = 0; j < 4; ++j) {
            f32x4 v = src[(base >> 2) + j];
            #pragma unroll
            for (int k = 0; k < 4; ++k) {
                float t = fminf(fmaxf(v[k] / sw, -QMAX_F), QMAX_F);
                q[j * 4 + k] = (int8_t)__float2int_rn(t);
            }
        }
        *reinterpret_cast<i8x16*>(dst + base) = q;
    }
}

// ---------------------------------------------------------------- GEMM
// C[M][N] = Aq[M][K] * Bq[N][K]^T   (int8 -> int32, exact) then dequant+bias
#define BM 128
#define BN 128
#define BKQ 64

__global__ __launch_bounds__(256) void gemm_i8_kernel(
        const int8_t* __restrict__ Aq, const int8_t* __restrict__ Bq,
        const unsigned* __restrict__ mx_bits, const float* __restrict__ scale_w,
        const float* __restrict__ bias, float* __restrict__ C,
        int M, int N, int K) {
    __shared__ __align__(16) int8_t lA[BM * BKQ];   // 8 KB
    __shared__ __align__(16) int8_t lB[BN * BKQ];   // 8 KB

    const int tid = threadIdx.x;
    const int l   = tid & 63;
    const int w   = tid >> 6;

    // XCD-aware swizzle (gridDim.x % 8 == 0 here: 128*32 = 4096)
    const int nwg = gridDim.x;
    const int wg  = (blockIdx.x & 7) * (nwg >> 3) + (blockIdx.x >> 3);
    const int tiles_n = N / BN;
    const int tm = wg / tiles_n, tn = wg % tiles_n;
    const size_t m0 = (size_t)tm * BM, n0 = (size_t)tn * BN;

    // --- staging: 8 chunks of 1024B per tile; wave w handles chunks w and w+4.
    // LDS dest is linear (global_load_lds writes base + lane*16); the global
    // SOURCE is inverse-swizzled so that reads can use the XOR-swizzled addr.
    const int8_t* gA[2]; const int8_t* gB[2];
    const int8_t* ldsA[2]; const int8_t* ldsB[2];
    #pragma unroll
    for (int i = 0; i < 2; ++i) {
        int c   = w + 4 * i;
        int row = c * 16 + (l >> 2);
        int g   = (l & 3) ^ ((row >> 1) & 3);        // logical k-slot fetched
        gA[i]   = Aq + (m0 + row) * (size_t)K + g * 16;
        gB[i]   = Bq + (n0 + row) * (size_t)K + g * 16;
        ldsA[i] = lA + c * 1024;                      // wave-uniform base
        ldsB[i] = lB + c * 1024;
    }

    // --- fragment read offsets (swizzled): phys slot = (l>>4) ^ f(row)
    const int wr = w >> 1, wc = w & 1;
    const int pbyte = (((l >> 4) ^ (((l & 15) >> 1) & 3)) << 4);
    int offA[4], offB[4];
    #pragma unroll
    for (int m = 0; m < 4; ++m) {
        offA[m] = (wr * 64 + m * 16 + (l & 15)) * BKQ + pbyte;
        offB[m] = (wc * 64 + m * 16 + (l & 15)) * BKQ + pbyte;
    }

    i32x4 acc[4][4];
    #pragma unroll
    for (int m = 0; m < 4; ++m)
        #pragma unroll
        for (int n = 0; n < 4; ++n)
            acc[m][n] = (i32x4){0, 0, 0, 0};

    for (int kt = 0; kt < K; kt += BKQ) {
        #pragma unroll
        for (int i = 0; i < 2; ++i) {
            __builtin_amdgcn_global_load_lds(GLOBAL_AS(gA[i] + kt), LDS_AS(ldsA[i]), 16, 0, 0);
            __builtin_amdgcn_global_load_lds(GLOBAL_AS(gB[i] + kt), LDS_AS(ldsB[i]), 16, 0, 0);
        }
        __syncthreads();   // compiler drains vmcnt(0) before s_barrier

        i32x4 af[4], bf[4];
        #pragma unroll
        for (int m = 0; m < 4; ++m)
            af[m] = *reinterpret_cast<const i32x4*>(lA + offA[m]);
        #pragma unroll
        for (int n = 0; n < 4; ++n)
            bf[n] = *reinterpret_cast<const i32x4*>(lB + offB[n]);

        #pragma unroll
        for (int m = 0; m < 4; ++m)
            #pragma unroll
            for (int n = 0; n < 4; ++n)
                acc[m][n] = __builtin_amdgcn_mfma_i32_16x16x64_i8(af[m], bf[n], acc[m][n], 0, 0, 0);

        __syncthreads();   // all waves done reading before next-stage overwrite
    }

    // --- epilogue: dequant + bias, fp32 out. C/D layout: col=l&15, row=(l>>4)*4+r
    float sx = fmaxf(__uint_as_float(*mx_bits), 1e-8f) / QMAX_F;
    const int colb = (int)n0 + wc * 64 + (l & 15);
    const int rowb = (int)m0 + wr * 64 + ((l >> 4) << 2);
    #pragma unroll
    for (int n = 0; n < 4; ++n) {
        int col = colb + n * 16;
        float s  = sx * scale_w[col];
        float bv = bias[col];
        #pragma unroll
        for (int m = 0; m < 4; ++m) {
            size_t base = (size_t)(rowb + m * 16) * N + col;
            #pragma unroll
            for (int r = 0; r < 4; ++r)
                C[base + (size_t)r * N] = (float)acc[m][n][r] * s + bv;
        }
    }
}

// ---------------------------------------------------------------- launch
extern "C" void kernel_launch(void* const* d_in, const int* in_sizes, int n_in,
                              void* d_out, int out_size, void* d_ws, size_t ws_size,
                              hipStream_t stream) {
    const float* x    = (const float*)d_in[0];
    const float* wt   = (const float*)d_in[1];
    const float* bias = (const float*)d_in[2];
    float* out        = (float*)d_out;

    const int N = in_sizes[2];                 // 4096
    const int K = in_sizes[1] / N;             // 4096
    const int M = in_sizes[0] / K;             // 16384
    const size_t nx = (size_t)in_sizes[0];     // 67,108,864
    const size_t nw = (size_t)in_sizes[1];     // 16,777,216

    uint8_t* ws = (uint8_t*)d_ws;
    unsigned* absmax_bits = (unsigned*)ws;                   // 4 B
    float*    rowmax      = (float*)(ws + 1024);             // N f32
    float*    scale_w     = (float*)(ws + 1024 + (size_t)N * 4 + 3072); // N f32
    int8_t*   xq          = (int8_t*)(ws + 65536);           // nx bytes
    int8_t*   wq          = xq + nx;                         // nw bytes

    hipLaunchKernelGGL(init_ws_kernel, dim3(1), dim3(64), 0, stream, absmax_bits);
    hipLaunchKernelGGL(absmax_x_kernel, dim3(2048), dim3(256), 0, stream,
                       x, nx / 4, absmax_bits);
    hipLaunchKernelGGL(rowmax_w_kernel, dim3(N), dim3(256), 0, stream,
                       wt, rowmax, K);
    hipLaunchKernelGGL(quant_x_kernel, dim3(4096), dim3(256), 0, stream,
                       x, xq, absmax_bits, nx / 16);
    hipLaunchKernelGGL(quant_w_kernel, dim3(N), dim3(256), 0, stream,
                       wt, wq, rowmax, scale_w, K);

    dim3 ggrid((M / BM) * (N / BN));
    hipLaunchKernelGGL(gemm_i8_kernel, ggrid, dim3(256), 0, stream,
                       xq, wq, absmax_bits, scale_w, bias, out, M, N, K);
}

// Round 2
// 799.398 us; speedup vs baseline: 1.1466x; 1.1466x over previous
//
#include <hip/hip_runtime.h>
#include <stdint.h>

#define QMAX_F 127.0f

typedef int    i32x4 __attribute__((ext_vector_type(4)));
typedef float  f32x4 __attribute__((ext_vector_type(4)));

#define GLOBAL_AS(p) ((const __attribute__((address_space(1))) void*)(p))
#define LDS_AS(p)    ((__attribute__((address_space(3))) void*)(p))

// ------------------------------------------------------ global absmax(x)
__global__ void absmax_x_kernel(const float* __restrict__ x, size_t n4,
                                unsigned* __restrict__ out_bits) {
    size_t stride = (size_t)gridDim.x * blockDim.x;
    float m = 0.f;
    for (size_t i = (size_t)blockIdx.x * blockDim.x + threadIdx.x; i < n4; i += stride) {
        f32x4 v = reinterpret_cast<const f32x4*>(x)[i];
        m = fmaxf(m, fmaxf(fmaxf(fabsf(v[0]), fabsf(v[1])),
                           fmaxf(fabsf(v[2]), fabsf(v[3]))));
    }
    #pragma unroll
    for (int off = 32; off > 0; off >>= 1) m = fmaxf(m, __shfl_down(m, off));
    __shared__ float red[4];
    int lane = threadIdx.x & 63, wid = threadIdx.x >> 6;
    if (lane == 0) red[wid] = m;
    __syncthreads();
    if (threadIdx.x == 0) {
        m = fmaxf(fmaxf(red[0], red[1]), fmaxf(red[2], red[3]));
        atomicMax(out_bits, __float_as_uint(m));
    }
}

// ------------------------------------------------------------ quantize x
__global__ void quant_x_kernel(const float* __restrict__ x, int8_t* __restrict__ xq,
                               const unsigned* __restrict__ mx_bits, size_t n16) {
    float sx = fmaxf(__uint_as_float(*mx_bits), 1e-8f) / QMAX_F;
    size_t stride = (size_t)gridDim.x * blockDim.x;
    for (size_t i = (size_t)blockIdx.x * blockDim.x + threadIdx.x; i < n16; i += stride) {
        uint32_t q[4];
        #pragma unroll
        for (int j = 0; j < 4; ++j) {
            f32x4 v = reinterpret_cast<const f32x4*>(x)[i * 4 + j];
            uint32_t p = 0;
            #pragma unroll
            for (int k = 0; k < 4; ++k) {
                float t = fminf(fmaxf(v[k] / sx, -QMAX_F), QMAX_F);
                p |= (uint32_t)(uint8_t)(int8_t)__float2int_rn(t) << (8 * k);
            }
            q[j] = p;
        }
        reinterpret_cast<i32x4*>(xq)[i] =
            (i32x4){(int)q[0], (int)q[1], (int)q[2], (int)q[3]};
    }
}

// ------------------------- fused per-row absmax + quantize of weight (K=4096)
__global__ __launch_bounds__(256) void wquant_kernel(const float* __restrict__ w,
        int8_t* __restrict__ wq, float* __restrict__ scale_w, int K) {
    int row = blockIdx.x;
    const f32x4* src = reinterpret_cast<const f32x4*>(w + (size_t)row * K);
    f32x4 v[4];
    float m = 0.f;
    #pragma unroll
    for (int j = 0; j < 4; ++j) {
        v[j] = src[threadIdx.x + j * 256];
        m = fmaxf(m, fmaxf(fmaxf(fabsf(v[j][0]), fabsf(v[j][1])),
                           fmaxf(fabsf(v[j][2]), fabsf(v[j][3]))));
    }
    #pragma unroll
    for (int off = 32; off > 0; off >>= 1) m = fmaxf(m, __shfl_down(m, off));
    __shared__ float red[5];
    int lane = threadIdx.x & 63, wid = threadIdx.x >> 6;
    if (lane == 0) red[wid] = m;
    __syncthreads();
    if (threadIdx.x == 0) {
        float mm = fmaxf(fmaxf(red[0], red[1]), fmaxf(red[2], red[3]));
        float sw = fmaxf(mm, 1e-8f) / QMAX_F;
        scale_w[row] = sw;
        red[4] = sw;
    }
    __syncthreads();
    float sw = red[4];
    uint32_t* dst = reinterpret_cast<uint32_t*>(wq + (size_t)row * K);
    #pragma unroll
    for (int j = 0; j < 4; ++j) {
        uint32_t p = 0;
        #pragma unroll
        for (int k = 0; k < 4; ++k) {
            float t = fminf(fmaxf(v[j][k] / sw, -QMAX_F), QMAX_F);
            p |= (uint32_t)(uint8_t)(int8_t)__float2int_rn(t) << (8 * k);
        }
        dst[threadIdx.x + j * 256] = p;
    }
}

// ---------------------------------------------------------------- GEMM
// C[M][N] = Aq[M][K] * Bq[N][K]^T  (int8 -> int32 exact), dequant+bias epilogue.
// 256x256 tile, BK=128, 8 waves (2Mx4N), per-wave 128x64 out, 8-phase schedule.
#define BM 256
#define BN 256
#define BK 128

#define LD128(p) (*reinterpret_cast<const i32x4*>(p))

__global__ __launch_bounds__(512, 2) void gemm_i8_kernel(
        const int8_t* __restrict__ Aq, const int8_t* __restrict__ Bq,
        const unsigned* __restrict__ mx_bits, const float* __restrict__ scale_w,
        const float* __restrict__ bias, float* __restrict__ C,
        int M, int N, int K) {
    __shared__ __align__(16) int8_t lA[2 * BM * BK];   // 64 KB (2 bufs)
    __shared__ __align__(16) int8_t lB[2 * BN * BK];   // 64 KB

    const int tid = threadIdx.x;
    const int l   = tid & 63;
    const int w   = tid >> 6;
    const int wr  = w >> 2, wc = w & 3;           // 2M x 4N wave grid
    const int NT  = K / BK;                       // 32

    // XCD-aware swizzle (nwg = 1024, divisible by 8)
    const int nwg = gridDim.x;
    const int wg  = (blockIdx.x & 7) * (nwg >> 3) + (blockIdx.x >> 3);
    const int tiles_n = N / BN;
    const int tm = wg / tiles_n, tn = wg % tiles_n;
    const size_t m0 = (size_t)tm * BM, n0 = (size_t)tn * BN;

    // ---- staging offsets. Half-tile = 128 rows x 128 B = 16 KB = 2 chunks/thread.
    // LDS fill is linear (chunk c at byte c*16): row = c>>3, phys slot p = c&7.
    // Content for phys slot p of row r is logical slot g = p ^ (r&7)  (T2 swizzle,
    // applied via inverse-swizzled GLOBAL source, rule #21).
    const int c0 = tid, c1 = 512 + tid;
    const int srow0 = c0 >> 3, srow1 = c1 >> 3;
    const int sgo0 = ((c0 & 7) ^ (srow0 & 7)) << 4;
    const int sgo1 = ((c1 & 7) ^ (srow1 & 7)) << 4;
    const size_t aoff0 = (m0 + srow0) * (size_t)K + sgo0;
    const size_t aoff1 = (m0 + srow1) * (size_t)K + sgo1;
    const size_t boff0 = (n0 + srow0) * (size_t)K + sgo0;
    const size_t boff1 = (n0 + srow1) * (size_t)K + sgo1;
    const int wbase = w * 1024;                   // wave-uniform LDS chunk base

#define STAGE_A(buf, half, tile) do {                                              \
    size_t t_ = (size_t)(((tile) < NT) ? (tile) : 0) * BK;                         \
    __builtin_amdgcn_global_load_lds(                                              \
        GLOBAL_AS(Aq + aoff0 + (size_t)(half) * 128 * K + t_),                     \
        LDS_AS(lA + (buf) * 32768 + (half) * 16384 + wbase), 16, 0, 0);            \
    __builtin_amdgcn_global_load_lds(                                              \
        GLOBAL_AS(Aq + aoff1 + (size_t)(half) * 128 * K + t_),                     \
        LDS_AS(lA + (buf) * 32768 + (half) * 16384 + 8192 + wbase), 16, 0, 0);     \
} while (0)

#define STAGE_B(buf, half, tile) do {                                              \
    size_t t_ = (size_t)(((tile) < NT) ? (tile) : 0) * BK;                         \
    __builtin_amdgcn_global_load_lds(                                              \
        GLOBAL_AS(Bq + boff0 + (size_t)(half) * 128 * K + t_),                     \
        LDS_AS(lB + (buf) * 32768 + (half) * 16384 + wbase), 16, 0, 0);            \
    __builtin_amdgcn_global_load_lds(                                              \
        GLOBAL_AS(Bq + boff1 + (size_t)(half) * 128 * K + t_),                     \
        LDS_AS(lB + (buf) * 32768 + (half) * 16384 + 8192 + wbase), 16, 0, 0);     \
} while (0)

    // ---- fragment read addressing (swizzled). Row byte stride = BK = 128.
    // A frag m, K-sub ks: lane reads row wr*128 + m*16 + (l&15),
    //   phys slot = (ks*4 + (l>>4)) ^ (l&7)   (row&7 == l&7 here).
    const int arow = (wr * 128 + (l & 15)) * BK;
    const int brow = (wc * 64  + (l & 15)) * BK;
    const int sl0  = (((l >> 4)    ) ^ (l & 7)) << 4;
    const int sl1  = (((l >> 4) + 4) ^ (l & 7)) << 4;
#define SLOT(ks) ((ks) ? sl1 : sl0)

    i32x4 acc[8][4] = {};
    i32x4 bf[2][4];

// One phase: {ds-read subtile; issue one half-tile stage; barrier; lgkmcnt(0);
//             setprio(1); 16 MFMA; setprio(0); [vmcnt tail]; barrier}
#define PHASE(buf, mh, ks, RB, STAGE_STMT, VMTAIL) do {                            \
    const int8_t* Ab_ = lA + (buf) * 32768 + arow;                                 \
    i32x4 a0_ = LD128(Ab_ + ((mh) * 4 + 0) * 2048 + SLOT(ks));                     \
    i32x4 a1_ = LD128(Ab_ + ((mh) * 4 + 1) * 2048 + SLOT(ks));                     \
    i32x4 a2_ = LD128(Ab_ + ((mh) * 4 + 2) * 2048 + SLOT(ks));                     \
    i32x4 a3_ = LD128(Ab_ + ((mh) * 4 + 3) * 2048 + SLOT(ks));                     \
    if ((RB) >= 0) {                                                               \
        const int8_t* Bb_ = lB + (buf) * 32768 + brow;                             \
        bf[(RB) & 1][0] = LD128(Bb_ + 0 * 2048 + SLOT((RB) & 1));                  \
        bf[(RB) & 1][1] = LD128(Bb_ + 1 * 2048 + SLOT((RB) & 1));                  \
        bf[(RB) & 1][2] = LD128(Bb_ + 2 * 2048 + SLOT((RB) & 1));                  \
        bf[(RB) & 1][3] = LD128(Bb_ + 3 * 2048 + SLOT((RB) & 1));                  \
    }                                                                              \
    STAGE_STMT;                                                                    \
    __builtin_amdgcn_s_barrier();                                                  \
    asm volatile("s_waitcnt lgkmcnt(0)" ::: "memory");                             \
    __builtin_amdgcn_s_setprio(1);                                                 \
    _Pragma("unroll") for (int n_ = 0; n_ < 4; ++n_) {                             \
        acc[(mh)*4+0][n_] = __builtin_amdgcn_mfma_i32_16x16x64_i8(a0_, bf[ks][n_], acc[(mh)*4+0][n_], 0, 0, 0); \
        acc[(mh)*4+1][n_] = __builtin_amdgcn_mfma_i32_16x16x64_i8(a1_, bf[ks][n_], acc[(mh)*4+1][n_], 0, 0, 0); \
        acc[(mh)*4+2][n_] = __builtin_amdgcn_mfma_i32_16x16x64_i8(a2_, bf[ks][n_], acc[(mh)*4+2][n_], 0, 0, 0); \
        acc[(mh)*4+3][n_] = __builtin_amdgcn_mfma_i32_16x16x64_i8(a3_, bf[ks][n_], acc[(mh)*4+3][n_], 0, 0, 0); \
    }                                                                              \
    __builtin_amdgcn_s_setprio(0);                                                 \
    VMTAIL;                                                                        \
    __builtin_amdgcn_s_barrier();                                                  \
    asm volatile("" ::: "memory");                                                 \
} while (0)

#define VMW4 asm volatile("s_waitcnt vmcnt(4)" ::: "memory")

    // ---- prologue: tile0 A+B -> buf0; tile1 B -> buf1  (12 loads/thread)
    STAGE_A(0, 0, 0); STAGE_A(0, 1, 0);
    STAGE_B(0, 0, 0); STAGE_B(0, 1, 0);
    STAGE_B(1, 0, 1); STAGE_B(1, 1, 1);
    VMW4;                                   // tile0 A+B landed; buf1.B may fly
    __builtin_amdgcn_s_barrier();
    asm volatile("" ::: "memory");

    #pragma unroll 1
    for (int i = 0; i < NT / 2; ++i) {
        const int t_a1 = 2 * i + 1;         // A for buf1, consumed this iter p4-7
        const int t_n  = 2 * i + 2;         // next K-tile -> buf0
        const int t_b3 = 2 * i + 3;         // B -> buf1, consumed next iter
        // ---- phases 0-3: compute buf0 (tile 2i)
        PHASE(0, 0, 0,  0, STAGE_A(1, 0, t_a1), );
        PHASE(0, 1, 0,  1, STAGE_A(1, 1, t_a1), );
        PHASE(0, 0, 1, -1, STAGE_B(0, 0, t_n),  );
        PHASE(0, 1, 1, -1, STAGE_B(0, 1, t_n),  VMW4);   // buf1 inputs landed
        // ---- phases 4-7: compute buf1 (tile 2i+1)
        PHASE(1, 0, 0,  0, STAGE_A(0, 0, t_n),  );
        PHASE(1, 1, 0,  1, STAGE_A(0, 1, t_n),  );
        PHASE(1, 0, 1, -1, STAGE_B(1, 0, t_b3), );
        PHASE(1, 1, 1, -1, STAGE_B(1, 1, t_b3), VMW4);   // buf0(t_n) landed
    }

    // ---- epilogue: dequant + bias. C/D layout: col=l&15, row=(l>>4)*4+r.
    float sx = fmaxf(__uint_as_float(*mx_bits), 1e-8f) / QMAX_F;
    const int colb  = (int)n0 + wc * 64 + (l & 15);
    const int rowb0 = (int)m0 + wr * 128 + ((l >> 4) << 2);
    #pragma unroll
    for (int n = 0; n < 4; ++n) {
        int col  = colb + n * 16;
        float s  = sx * scale_w[col];
        float bv = bias[col];
        #pragma unroll
        for (int m = 0; m < 8; ++m) {
            size_t base = (size_t)(rowb0 + m * 16) * N + col;
            #pragma unroll
            for (int r = 0; r < 4; ++r)
                C[base + (size_t)r * N] = (float)acc[m][n][r] * s + bv;
        }
    }
}

// ---------------------------------------------------------------- launch
extern "C" void kernel_launch(void* const* d_in, const int* in_sizes, int n_in,
                              void* d_out, int out_size, void* d_ws, size_t ws_size,
                              hipStream_t stream) {
    const float* x    = (const float*)d_in[0];
    const float* wt   = (const float*)d_in[1];
    const float* bias = (const float*)d_in[2];
    float* out        = (float*)d_out;

    const int N = in_sizes[2];                 // 4096
    const int K = in_sizes[1] / N;             // 4096
    const int M = in_sizes[0] / K;             // 16384
    const size_t nx = (size_t)in_sizes[0];
    const size_t nw = (size_t)in_sizes[1];

    uint8_t* ws = (uint8_t*)d_ws;
    unsigned* absmax_bits = (unsigned*)ws;
    float*    scale_w     = (float*)(ws + 4096);
    int8_t*   xq          = (int8_t*)(ws + 65536);
    int8_t*   wq          = xq + nx;

    hipMemsetAsync(absmax_bits, 0, 4, stream);
    hipLaunchKernelGGL(absmax_x_kernel, dim3(2048), dim3(256), 0, stream,
                       x, nx / 4, absmax_bits);
    hipLaunchKernelGGL(wquant_kernel, dim3(N), dim3(256), 0, stream,
                       wt, wq, scale_w, K);
    hipLaunchKernelGGL(quant_x_kernel, dim3(4096), dim3(256), 0, stream,
                       x, xq, absmax_bits, nx / 16);

    dim3 ggrid((M / BM) * (N / BN));
    hipLaunchKernelGGL(gemm_i8_kernel, ggrid, dim3(512), 0, stream,
                       xq, wq, absmax_bits, scale_w, bias, out, M, N, K);
}